// Round 1
// 796.317 us; speedup vs baseline: 1.0404x; 1.0404x over previous
//
#include <hip/hip_runtime.h>

// HypergraphGuidedChebNet on MI355X.
//   1. zero replicated counters  2. degrees (XCD-replicated atomics + rank capture)
//   3. replica-offset combine  4. scans  5. fill CSR (atomic-free)  6. norms2
//   7. init (pre-scaled V0 = dv*x)  8. 10x [phaseA edge-gather, phaseB node-gather]
//   9. bf16 MFMA GEMM (fp32->bf16 cast in staging), XCD-banded swizzle
//
// Round 8 theory:
//   - k_degrees (66us, top dispatch) was cross-XCD atomic-bound: 64B-padded
//     counters -> 51MB line writeback + every line shared by 8 XCDs.
//     Replicate counters 8x (blockIdx&7 ~ XCD round-robin): atomics stay in
//     the local L2, unpadded, 8x less same-address contention. Ranks pack
//     replica id in bits [24..); k_off8 builds per-replica offsets + totals.
//   - phase loop: buffers now hold V = dv_is*T (w=1 for isolated nodes) so
//     phaseA drops the 800K-per-pass random dv_is gathers; phaseB applies
//     ca*dv^2 and accumulates theta*V/dv. phaseA unrolled 4 rows in flight
//     per lane-stream for latency hiding.

#define N_NODES 50000
#define N_EDGES 10000
#define NNZ     800000
#define F_IN    128
#define HID     512
#define F4      (F_IN / 4)
#define R16     16           // 16 uint4 per bf16 row

typedef __attribute__((ext_vector_type(8))) short bf16x8;
typedef __attribute__((ext_vector_type(4))) float f32x4;

static __device__ __forceinline__ unsigned short f2bf(float f) {
    union { float f; unsigned u; } c; c.f = f;
    unsigned u = c.u;
    unsigned r = (u + 0x7fffu + ((u >> 16) & 1u)) >> 16;
    return (unsigned short)r;
}
static __device__ __forceinline__ float blo(unsigned u) {
    union { unsigned u; float f; } c; c.u = u << 16; return c.f;
}
static __device__ __forceinline__ float bhi(unsigned u) {
    union { unsigned u; float f; } c; c.u = u & 0xffff0000u; return c.f;
}
static __device__ __forceinline__ unsigned pack2(float lo, float hi) {
    return (unsigned)f2bf(lo) | ((unsigned)f2bf(hi) << 16);
}

// ---------------------------------------------------------------- zero replicated counters
__global__ void k_zero8(int* __restrict__ cnt8_e, int* __restrict__ cnt8_n) {
    int i = blockIdx.x * blockDim.x + threadIdx.x;
    if (i < 8 * N_NODES) cnt8_n[i] = 0;
    if (i < 8 * N_EDGES) cnt8_e[i] = 0;
}

// ---------------------------------------------------------------- degrees + rank capture
// Each block atomics into replica (blockIdx&7); with round-robin dispatch that
// replica's lines live exclusively in the local XCD L2.
__global__ void k_degrees(const int* __restrict__ hidx,
                          int* __restrict__ cnt8_e,
                          int* __restrict__ cnt8_n,
                          int* __restrict__ rank_e,
                          int* __restrict__ rank_v) {
    int i = blockIdx.x * blockDim.x + threadIdx.x;
    if (i >= NNZ) return;
    int xcd = (int)blockIdx.x & 7;
    int v = hidx[i];
    int e = hidx[NNZ + i];
    v = min(max(v, 0), N_NODES - 1);
    e = min(max(e, 0), N_EDGES - 1);
    int re = atomicAdd(&cnt8_e[xcd * N_EDGES + e], 1);
    int rv = atomicAdd(&cnt8_n[xcd * N_NODES + v], 1);
    rank_e[i] = re | (xcd << 24);
    rank_v[i] = rv | (xcd << 24);
}

// ---------------------------------------------------------------- replica combine
// In-place: cnt8 -> exclusive per-replica offsets; totals -> counts arrays.
__global__ void k_off8(int* __restrict__ cnt8_e,
                       int* __restrict__ cnt8_n,
                       int* __restrict__ counts_e,
                       int* __restrict__ counts_n) {
    int i = blockIdx.x * blockDim.x + threadIdx.x;
    if (i < N_EDGES) {
        int s = 0;
#pragma unroll
        for (int x = 0; x < 8; ++x) {
            int c = cnt8_e[x * N_EDGES + i];
            cnt8_e[x * N_EDGES + i] = s;
            s += c;
        }
        counts_e[i] = s;
    }
    if (i < N_NODES) {
        int s = 0;
#pragma unroll
        for (int x = 0; x < 8; ++x) {
            int c = cnt8_n[x * N_NODES + i];
            cnt8_n[x * N_NODES + i] = s;
            s += c;
        }
        counts_n[i] = s;
    }
}

// ---------------------------------------------------------------- scan p1
__global__ __launch_bounds__(1024) void k_scan_blk(const int* __restrict__ counts, int n,
                                                   int stride,
                                                   int* __restrict__ out,
                                                   int* __restrict__ partial) {
    __shared__ int sd[1024];
    int tid = (int)threadIdx.x;
    int i = blockIdx.x * 1024 + tid;
    int v = (i < n) ? counts[(size_t)i * stride] : 0;
    sd[tid] = v;
    __syncthreads();
    for (int off = 1; off < 1024; off <<= 1) {
        int t = (tid >= off) ? sd[tid - off] : 0;
        __syncthreads();
        sd[tid] += t;
        __syncthreads();
    }
    if (i < n) out[i] = sd[tid] - v;
    if (tid == 1023) partial[blockIdx.x] = sd[1023];
}

// ---------------------------------------------------------------- scan p2 (nb <= 64)
__global__ void k_scan_top(int* __restrict__ partial, int nb, int* __restrict__ total_out) {
    int lane = (int)threadIdx.x;
    int v = (lane < nb) ? partial[lane] : 0;
    int incl = v;
    for (int off = 1; off < 64; off <<= 1) {
        int t = __shfl_up(incl, off);
        if (lane >= off) incl += t;
    }
    if (lane < nb) partial[lane] = incl - v;
    if (lane == 63) *total_out = incl;
}

// ---------------------------------------------------------------- scan p3
__global__ __launch_bounds__(1024) void k_scan_add(int* __restrict__ out, int n,
                                                   const int* __restrict__ partial) {
    int i = blockIdx.x * 1024 + (int)threadIdx.x;
    if (i < n) out[i] += partial[blockIdx.x];
}

// ---------------------------------------------------------------- CSR fill (atomic-free)
__global__ void k_fill(const int* __restrict__ hidx,
                       const int* __restrict__ edge_ptr,
                       const int* __restrict__ node_ptr,
                       const int* __restrict__ rank_e,
                       const int* __restrict__ rank_v,
                       const int* __restrict__ off8_e,
                       const int* __restrict__ off8_n,
                       int* __restrict__ edge_node,
                       int* __restrict__ node_edge) {
    int i = blockIdx.x * blockDim.x + threadIdx.x;
    if (i >= NNZ) return;
    int v = hidx[i];
    int e = hidx[NNZ + i];
    v = min(max(v, 0), N_NODES - 1);
    e = min(max(e, 0), N_EDGES - 1);
    int pe = rank_e[i];
    int pv = rank_v[i];
    int xe = pe >> 24, re = pe & 0xFFFFFF;
    int xv = pv >> 24, rv = pv & 0xFFFFFF;
    edge_node[edge_ptr[e] + off8_e[xe * N_EDGES + e] + re] = v;
    node_edge[node_ptr[v] + off8_n[xv * N_NODES + v] + rv] = e;
}

// ---------------------------------------------------------------- norms from CSR
__global__ void k_norms2(const float* __restrict__ ew,
                         const int* __restrict__ edge_ptr,
                         const int* __restrict__ node_ptr,
                         const int* __restrict__ node_edge,
                         float* __restrict__ dv_is,
                         float* __restrict__ de_w) {
    int i = blockIdx.x * blockDim.x + threadIdx.x;
    if (i < N_NODES) {
        int s = node_ptr[i], t = node_ptr[i + 1];
        float d = 0.f;
        for (int j = s; j < t; ++j) d += ew[node_edge[j]];
        dv_is[i] = (d > 0.f) ? rsqrtf(fmaxf(d, 1e-12f)) : 0.f;
    }
    if (i < N_EDGES) {
        int c = edge_ptr[i + 1] - edge_ptr[i];
        de_w[i] = ew[i] * ((c > 0) ? (1.f / (float)c) : 0.f);
    }
}

// ---------------------------------------------------------------- init
// Buffers hold V = w*T with w = dv_is (or 1 for isolated nodes, which phaseA
// never gathers). acc holds true theta0*x.
__global__ void k_init(const float* __restrict__ x,
                       const float* __restrict__ theta,
                       const float* __restrict__ dv_is,
                       uint4* __restrict__ bufA,
                       float* __restrict__ acc) {
    int i = blockIdx.x * blockDim.x + threadIdx.x;
    if (i >= N_NODES * R16) return;
    int v = i >> 4;
    float dvv = dv_is[v];
    float w = (dvv > 0.f) ? dvv : 1.f;
    float4 x0 = ((const float4*)x)[2 * i];
    float4 x1 = ((const float4*)x)[2 * i + 1];
    uint4 q;
    q.x = pack2(w * x0.x, w * x0.y); q.y = pack2(w * x0.z, w * x0.w);
    q.z = pack2(w * x1.x, w * x1.y); q.w = pack2(w * x1.z, w * x1.w);
    bufA[i] = q;
    float t0 = theta[0];
    float4 a0, a1;
    a0.x = t0 * x0.x; a0.y = t0 * x0.y; a0.z = t0 * x0.z; a0.w = t0 * x0.w;
    a1.x = t0 * x1.x; a1.y = t0 * x1.y; a1.z = t0 * x1.z; a1.w = t0 * x1.w;
    ((float4*)acc)[2 * i]     = a0;
    ((float4*)acc)[2 * i + 1] = a1;
}

// ---------------------------------------------------------------- phase A
// 8 edges/block; per edge 32 lanes = 2 member-streams x 16 feature-lanes.
// Rows are pre-scaled (V = dv*T): pure unweighted row-sum, 4 rows in flight
// per lane-stream.
__global__ void k_phaseA(const uint4* __restrict__ tin,
                         const float* __restrict__ de_w,
                         const int* __restrict__ edge_ptr,
                         const int* __restrict__ edge_node,
                         uint4* __restrict__ m_e) {
    int g      = threadIdx.x >> 5;
    int stream = (threadIdx.x >> 4) & 1;
    int lane   = threadIdx.x & 15;
    int e = blockIdx.x * 8 + g;
    int s = edge_ptr[e], t = edge_ptr[e + 1];
    float a0=0.f,a1=0.f,a2=0.f,a3=0.f,a4=0.f,a5=0.f,a6=0.f,a7=0.f;
    int j = s + stream;
    for (; j + 6 < t; j += 8) {   // unroll-4 per stream (stride-2 members)
        int v0 = edge_node[j];
        int v1 = edge_node[j + 2];
        int v2 = edge_node[j + 4];
        int v3 = edge_node[j + 6];
        uint4 q0 = tin[v0 * R16 + lane];
        uint4 q1 = tin[v1 * R16 + lane];
        uint4 q2 = tin[v2 * R16 + lane];
        uint4 q3 = tin[v3 * R16 + lane];
        a0 += (blo(q0.x) + blo(q1.x)) + (blo(q2.x) + blo(q3.x));
        a1 += (bhi(q0.x) + bhi(q1.x)) + (bhi(q2.x) + bhi(q3.x));
        a2 += (blo(q0.y) + blo(q1.y)) + (blo(q2.y) + blo(q3.y));
        a3 += (bhi(q0.y) + bhi(q1.y)) + (bhi(q2.y) + bhi(q3.y));
        a4 += (blo(q0.z) + blo(q1.z)) + (blo(q2.z) + blo(q3.z));
        a5 += (bhi(q0.z) + bhi(q1.z)) + (bhi(q2.z) + bhi(q3.z));
        a6 += (blo(q0.w) + blo(q1.w)) + (blo(q2.w) + blo(q3.w));
        a7 += (bhi(q0.w) + bhi(q1.w)) + (bhi(q2.w) + bhi(q3.w));
    }
    for (; j < t; j += 2) {
        int v0 = edge_node[j];
        uint4 q0 = tin[v0 * R16 + lane];
        a0 += blo(q0.x); a1 += bhi(q0.x);
        a2 += blo(q0.y); a3 += bhi(q0.y);
        a4 += blo(q0.z); a5 += bhi(q0.z);
        a6 += blo(q0.w); a7 += bhi(q0.w);
    }
    // combine the two streams (lane L <-> L^16)
    a0 += __shfl_xor(a0, 16); a1 += __shfl_xor(a1, 16);
    a2 += __shfl_xor(a2, 16); a3 += __shfl_xor(a3, 16);
    a4 += __shfl_xor(a4, 16); a5 += __shfl_xor(a5, 16);
    a6 += __shfl_xor(a6, 16); a7 += __shfl_xor(a7, 16);
    if (stream == 0) {
        float w = de_w[e];
        uint4 o;
        o.x = pack2(a0 * w, a1 * w); o.y = pack2(a2 * w, a3 * w);
        o.z = pack2(a4 * w, a5 * w); o.w = pack2(a6 * w, a7 * w);
        m_e[e * R16 + lane] = o;
    }
}

// ---------------------------------------------------------------- phase B
// 8 nodes/block; per node 32 lanes = 2 edge-streams x 16 feature-lanes.
// V_k = ca*dv^2*sum + cb*V_{k-2};  acc += theta_k * V_k / w.
__global__ void k_phaseB(const uint4* __restrict__ m_e,
                         const float* __restrict__ dv_is,
                         const int* __restrict__ node_ptr,
                         const int* __restrict__ node_edge,
                         uint4* __restrict__ tio,
                         float* __restrict__ acc,
                         const float* __restrict__ theta, int k,
                         float ca, float cb) {
    int g      = threadIdx.x >> 5;
    int stream = (threadIdx.x >> 4) & 1;
    int lane   = threadIdx.x & 15;
    int v = blockIdx.x * 8 + g;
    int s = node_ptr[v], t = node_ptr[v + 1];
    float s0=0.f,s1=0.f,s2=0.f,s3=0.f,s4=0.f,s5=0.f,s6=0.f,s7=0.f;
    int j = s + stream;
    for (; j + 2 < t; j += 4) {
        int e0 = node_edge[j];
        int e1 = node_edge[j + 2];
        uint4 q0 = m_e[e0 * R16 + lane];
        uint4 q1 = m_e[e1 * R16 + lane];
        s0 += blo(q0.x) + blo(q1.x); s1 += bhi(q0.x) + bhi(q1.x);
        s2 += blo(q0.y) + blo(q1.y); s3 += bhi(q0.y) + bhi(q1.y);
        s4 += blo(q0.z) + blo(q1.z); s5 += bhi(q0.z) + bhi(q1.z);
        s6 += blo(q0.w) + blo(q1.w); s7 += bhi(q0.w) + bhi(q1.w);
    }
    if (j < t) {
        int e0 = node_edge[j];
        uint4 q0 = m_e[e0 * R16 + lane];
        s0 += blo(q0.x); s1 += bhi(q0.x);
        s2 += blo(q0.y); s3 += bhi(q0.y);
        s4 += blo(q0.z); s5 += bhi(q0.z);
        s6 += blo(q0.w); s7 += bhi(q0.w);
    }
    s0 += __shfl_xor(s0, 16); s1 += __shfl_xor(s1, 16);
    s2 += __shfl_xor(s2, 16); s3 += __shfl_xor(s3, 16);
    s4 += __shfl_xor(s4, 16); s5 += __shfl_xor(s5, 16);
    s6 += __shfl_xor(s6, 16); s7 += __shfl_xor(s7, 16);
    if (stream == 0) {
        float dvv = dv_is[v];
        float scf = ca * dvv * dvv;           // 0 for isolated nodes (sum=0 anyway)
        float iw  = (dvv > 0.f) ? (1.f / dvv) : 1.f;
        float thinv = theta[k] * iw;
        int idx = v * R16 + lane;
        uint4 tp = tio[idx];
        float t0 = scf * s0 + cb * blo(tp.x);
        float t1 = scf * s1 + cb * bhi(tp.x);
        float t2 = scf * s2 + cb * blo(tp.y);
        float t3 = scf * s3 + cb * bhi(tp.y);
        float t4 = scf * s4 + cb * blo(tp.z);
        float t5 = scf * s5 + cb * bhi(tp.z);
        float t6 = scf * s6 + cb * blo(tp.w);
        float t7 = scf * s7 + cb * bhi(tp.w);
        uint4 tn;
        tn.x = pack2(t0, t1); tn.y = pack2(t2, t3);
        tn.z = pack2(t4, t5); tn.w = pack2(t6, t7);
        tio[idx] = tn;
        float4* acc4 = (float4*)acc;
        int ai = v * 32 + lane * 2;
        float4 a = acc4[ai];
        a.x += thinv * t0; a.y += thinv * t1; a.z += thinv * t2; a.w += thinv * t3;
        acc4[ai] = a;
        float4 b = acc4[ai + 1];
        b.x += thinv * t4; b.y += thinv * t5; b.z += thinv * t6; b.w += thinv * t7;
        acc4[ai + 1] = b;
    }
}

// ---------------------------------------------------------------- MFMA GEMM
// out = relu(A @ W^T + b), A=accv fp32 [M][128], W fp32 [512][128].
// Block: 256thr=4 waves, tile M=64 N=64, K=128 fully staged.
// fp32->bf16 cast during LDS staging (no extra buffers).
// LDS row = 136 shorts (272B): lane bank spread uniform -> conflict-free.
// XCD swizzle: id&7 = band; each band owns 98 contiguous m-tiles.
#define M_TILES 782
__global__ __launch_bounds__(256) void k_gemm(const float* __restrict__ A,
                                              const float* __restrict__ W,
                                              const float* __restrict__ bias,
                                              float* __restrict__ out) {
    __shared__ short Asm[64 * 136];
    __shared__ short Wsm[64 * 136];
    int id  = (int)blockIdx.x;
    int xcd = id & 7;
    int sub = id >> 3;
    int h_t = sub & 7;
    int m_i = sub >> 3;                 // 0..97
    int m_t = xcd * 98 + m_i;
    if (m_t >= M_TILES) return;
    int m0 = m_t * 64;
    int h0 = h_t * 64;
    int tid = (int)threadIdx.x;

    const float4* A4 = (const float4*)A;
    const float4* W4 = (const float4*)W;
#pragma unroll
    for (int i = 0; i < 4; ++i) {
        int c   = tid + i * 256;        // 0..1023
        int row = c >> 4;               // 0..63
        int q4  = c & 15;               // uint4 column
        int gr = m0 + row;
        float4 a0, a1;
        if (gr < N_NODES) {
            a0 = A4[(size_t)gr * 32 + q4 * 2];
            a1 = A4[(size_t)gr * 32 + q4 * 2 + 1];
        } else {
            a0 = make_float4(0.f, 0.f, 0.f, 0.f);
            a1 = a0;
        }
        uint4 pa;
        pa.x = pack2(a0.x, a0.y); pa.y = pack2(a0.z, a0.w);
        pa.z = pack2(a1.x, a1.y); pa.w = pack2(a1.z, a1.w);
        *(uint4*)&Asm[row * 136 + q4 * 8] = pa;
        float4 w0 = W4[(size_t)(h0 + row) * 32 + q4 * 2];
        float4 w1 = W4[(size_t)(h0 + row) * 32 + q4 * 2 + 1];
        uint4 pw;
        pw.x = pack2(w0.x, w0.y); pw.y = pack2(w0.z, w0.w);
        pw.z = pack2(w1.x, w1.y); pw.w = pack2(w1.z, w1.w);
        *(uint4*)&Wsm[row * 136 + q4 * 8] = pw;
    }
    __syncthreads();

    int lane = tid & 63;
    int wv   = tid >> 6;                // wave 0..3 -> m rows wv*16..+15
    int l16  = lane & 15;
    int quad = lane >> 4;

    f32x4 acc[4];
#pragma unroll
    for (int n = 0; n < 4; ++n) acc[n] = (f32x4){0.f, 0.f, 0.f, 0.f};

#pragma unroll
    for (int ks = 0; ks < 4; ++ks) {
        int k0 = ks * 32;
        // A-frag: A[m = l16][k = quad*8 + j]
        bf16x8 af = *(const bf16x8*)&Asm[(wv * 16 + l16) * 136 + k0 + quad * 8];
#pragma unroll
        for (int n = 0; n < 4; ++n) {
            bf16x8 bf = *(const bf16x8*)&Wsm[(n * 16 + l16) * 136 + k0 + quad * 8];
            acc[n] = __builtin_amdgcn_mfma_f32_16x16x32_bf16(af, bf, acc[n], 0, 0, 0);
        }
    }

    // C/D layout: col = lane&15, row = quad*4 + reg   (m89/m91-verified)
#pragma unroll
    for (int n = 0; n < 4; ++n) {
        float bb = bias[h0 + n * 16 + l16];
#pragma unroll
        for (int r = 0; r < 4; ++r) {
            int gr = m0 + wv * 16 + quad * 4 + r;
            if (gr < N_NODES)
                out[(size_t)gr * HID + h0 + n * 16 + l16] =
                    fmaxf(acc[n][r] + bb, 0.f);
        }
    }
}

// ----------------------------------------------------------------
extern "C" void kernel_launch(void* const* d_in, const int* in_sizes, int n_in,
                              void* d_out, int out_size, void* d_ws, size_t ws_size,
                              hipStream_t stream) {
    const float* x     = (const float*)d_in[0];
    const int*   hidx  = (const int*)d_in[1];    // int32, [2, NNZ] row-major
    const float* ew    = (const float*)d_in[2];
    const float* theta = (const float*)d_in[3];
    const float* w1    = (const float*)d_in[4];
    const float* b1    = (const float*)d_in[5];
    float*       out   = (float*)d_out;
    int kp1 = in_sizes[3];  // K+1 (= 11)

    // ---- scratch carved out of d_out (all dead before k_gemm's writes) ----
    char* ob = (char*)d_out;
    size_t oo = 0;
    auto oalloc = [&](size_t bytes) -> void* {
        void* p = ob + oo;
        oo = (oo + bytes + 255) & ~(size_t)255;
        return p;
    };
    uint4* bufA      = (uint4*)oalloc((size_t)N_NODES * F_IN * 2);
    uint4* bufB      = (uint4*)oalloc((size_t)N_NODES * F_IN * 2);
    uint4* m_e       = (uint4*)oalloc((size_t)N_EDGES * F_IN * 2);
    int*   edge_node = (int*)oalloc((size_t)NNZ * 4);
    int*   node_edge = (int*)oalloc((size_t)NNZ * 4);
    int*   rank_e    = (int*)oalloc((size_t)NNZ * 4);
    int*   rank_v    = (int*)oalloc((size_t)NNZ * 4);
    int*   cnt8_e    = (int*)oalloc((size_t)8 * N_EDGES * 4);   // -> off8_e
    int*   cnt8_n    = (int*)oalloc((size_t)8 * N_NODES * 4);   // -> off8_n
    int*   counts_e  = (int*)oalloc((size_t)N_EDGES * 4);
    int*   counts_n  = (int*)oalloc((size_t)N_NODES * 4);

    // ---- d_ws (~26MB) ----
    char* ws = (char*)d_ws;
    size_t off = 0;
    auto alloc = [&](size_t bytes) -> void* {
        void* p = ws + off;
        off = (off + bytes + 255) & ~(size_t)255;
        return p;
    };
    float* accv     = (float*)alloc((size_t)N_NODES * F_IN * 4);
    float* dv_is    = (float*)alloc((size_t)N_NODES * 4);
    float* de_w     = (float*)alloc((size_t)N_EDGES * 4);
    int*   edge_ptr = (int*)alloc((size_t)(N_EDGES + 1) * 4);
    int*   node_ptr = (int*)alloc((size_t)(N_NODES + 1) * 4);
    int*   part_e   = (int*)alloc(64 * 4);
    int*   part_n   = (int*)alloc(64 * 4);

    const int NB_E = (N_EDGES + 1023) / 1024;   // 10
    const int NB_N = (N_NODES + 1023) / 1024;   // 49

    k_zero8<<<(8 * N_NODES + 255) / 256, 256, 0, stream>>>(cnt8_e, cnt8_n);
    k_degrees<<<(NNZ + 255) / 256, 256, 0, stream>>>(hidx, cnt8_e, cnt8_n, rank_e, rank_v);
    k_off8<<<(N_NODES + 255) / 256, 256, 0, stream>>>(cnt8_e, cnt8_n, counts_e, counts_n);

    k_scan_blk<<<NB_E, 1024, 0, stream>>>(counts_e, N_EDGES, 1, edge_ptr, part_e);
    k_scan_top<<<1, 64, 0, stream>>>(part_e, NB_E, edge_ptr + N_EDGES);
    k_scan_add<<<NB_E, 1024, 0, stream>>>(edge_ptr, N_EDGES, part_e);

    k_scan_blk<<<NB_N, 1024, 0, stream>>>(counts_n, N_NODES, 1, node_ptr, part_n);
    k_scan_top<<<1, 64, 0, stream>>>(part_n, NB_N, node_ptr + N_NODES);
    k_scan_add<<<NB_N, 1024, 0, stream>>>(node_ptr, N_NODES, part_n);

    k_fill<<<(NNZ + 255) / 256, 256, 0, stream>>>(hidx, edge_ptr, node_ptr,
                                                  rank_e, rank_v, cnt8_e, cnt8_n,
                                                  edge_node, node_edge);
    k_norms2<<<(N_NODES + 255) / 256, 256, 0, stream>>>(ew, edge_ptr, node_ptr,
                                                        node_edge, dv_is, de_w);
    k_init<<<(N_NODES * R16 + 255) / 256, 256, 0, stream>>>(x, theta, dv_is, bufA, accv);

    for (int k = 1; k < kp1; ++k) {
        const uint4* tin = (k & 1) ? bufA : bufB;   // V_{k-1}
        uint4*       tio = (k & 1) ? bufB : bufA;   // V_{k-2} -> V_k
        float ca = (k == 1) ? -1.f : -2.f;
        float cb = (k == 1) ? 0.f : -1.f;
        k_phaseA<<<N_EDGES / 8, 256, 0, stream>>>(tin, de_w, edge_ptr, edge_node, m_e);
        k_phaseB<<<N_NODES / 8, 256, 0, stream>>>(m_e, dv_is, node_ptr, node_edge,
                                                  tio, accv, theta, k, ca, cb);
    }

    // 8 bands x 98 m-tiles x 8 h-tiles (2 tail tiles early-return)
    k_gemm<<<8 * 98 * 8, 256, 0, stream>>>(accv, w1, b1, out);
}

// Round 2
// 774.237 us; speedup vs baseline: 1.0700x; 1.0285x over previous
//
#include <hip/hip_runtime.h>

// HypergraphGuidedChebNet on MI355X.
//   1. zero replicated counters  2. degrees (XCD-replicated atomics + rank capture)
//   3. replica-offset combine  4. fused scans  5. fill CSR (atomic-free)  6. norms2
//   7. init (pre-scaled V0 = dv*x)  8. 10x [phaseA edge-gather (4-stream waves),
//      phaseB node-gather with GROUPED theta accumulation (k=3,6,9: 3 terms, k=10: 1)]
//   9. bf16 MFMA GEMM (fp32->bf16 cast in staging), XCD-banded swizzle
//
// Round 9 theory:
//   - k_degrees is atomic-rate bound (~25G/s, WRITE_SIZE 56MB = 1.6M x 32B
//     write-through): replication didn't help -> accept as floor.
//   - phaseB acc RMW (51.2MB x 10) carried one theta term each. Ping-pong
//     in-place read means V_{k-2} is free in registers: group 3 theta terms
//     per RMW (steps k=3,6,9 + tail k=10). 563MB -> 243MB acc traffic.
//   - phaseA: 1 wave per edge, 4 streams x 16 lanes, grid 2500 -> 32 waves/CU
//     (was 19.5), 16 row-gathers in flight per edge.
//   - scans fused 6 -> 3 dispatches.

#define N_NODES 50000
#define N_EDGES 10000
#define NNZ     800000
#define F_IN    128
#define HID     512
#define F4      (F_IN / 4)
#define R16     16           // 16 uint4 per bf16 row
#define NB_E    10           // scan blocks, edges
#define NB_N    49           // scan blocks, nodes

typedef __attribute__((ext_vector_type(8))) short bf16x8;
typedef __attribute__((ext_vector_type(4))) float f32x4;

static __device__ __forceinline__ unsigned short f2bf(float f) {
    union { float f; unsigned u; } c; c.f = f;
    unsigned u = c.u;
    unsigned r = (u + 0x7fffu + ((u >> 16) & 1u)) >> 16;
    return (unsigned short)r;
}
static __device__ __forceinline__ float blo(unsigned u) {
    union { unsigned u; float f; } c; c.u = u << 16; return c.f;
}
static __device__ __forceinline__ float bhi(unsigned u) {
    union { unsigned u; float f; } c; c.u = u & 0xffff0000u; return c.f;
}
static __device__ __forceinline__ unsigned pack2(float lo, float hi) {
    return (unsigned)f2bf(lo) | ((unsigned)f2bf(hi) << 16);
}

// ---------------------------------------------------------------- zero replicated counters
__global__ void k_zero8(int* __restrict__ cnt8_e, int* __restrict__ cnt8_n) {
    int i = blockIdx.x * blockDim.x + threadIdx.x;
    if (i < 8 * N_NODES) cnt8_n[i] = 0;
    if (i < 8 * N_EDGES) cnt8_e[i] = 0;
}

// ---------------------------------------------------------------- degrees + rank capture
__global__ void k_degrees(const int* __restrict__ hidx,
                          int* __restrict__ cnt8_e,
                          int* __restrict__ cnt8_n,
                          int* __restrict__ rank_e,
                          int* __restrict__ rank_v) {
    int i = blockIdx.x * blockDim.x + threadIdx.x;
    if (i >= NNZ) return;
    int xcd = (int)blockIdx.x & 7;
    int v = hidx[i];
    int e = hidx[NNZ + i];
    v = min(max(v, 0), N_NODES - 1);
    e = min(max(e, 0), N_EDGES - 1);
    int re = atomicAdd(&cnt8_e[xcd * N_EDGES + e], 1);
    int rv = atomicAdd(&cnt8_n[xcd * N_NODES + v], 1);
    rank_e[i] = re | (xcd << 24);
    rank_v[i] = rv | (xcd << 24);
}

// ---------------------------------------------------------------- replica combine
__global__ void k_off8(int* __restrict__ cnt8_e,
                       int* __restrict__ cnt8_n,
                       int* __restrict__ counts_e,
                       int* __restrict__ counts_n) {
    int i = blockIdx.x * blockDim.x + threadIdx.x;
    if (i < N_EDGES) {
        int s = 0;
#pragma unroll
        for (int x = 0; x < 8; ++x) {
            int c = cnt8_e[x * N_EDGES + i];
            cnt8_e[x * N_EDGES + i] = s;
            s += c;
        }
        counts_e[i] = s;
    }
    if (i < N_NODES) {
        int s = 0;
#pragma unroll
        for (int x = 0; x < 8; ++x) {
            int c = cnt8_n[x * N_NODES + i];
            cnt8_n[x * N_NODES + i] = s;
            s += c;
        }
        counts_n[i] = s;
    }
}

// ---------------------------------------------------------------- fused scan p1 (edges+nodes)
__global__ __launch_bounds__(1024) void k_scan_blk2(const int* __restrict__ ce,
                                                    const int* __restrict__ cn,
                                                    int* __restrict__ oute,
                                                    int* __restrict__ outn,
                                                    int* __restrict__ pe,
                                                    int* __restrict__ pn) {
    __shared__ int sd[1024];
    int b = (int)blockIdx.x;
    const int* counts; int n; int* out; int* partial; int lb;
    if (b < NB_E) { counts = ce; n = N_EDGES; out = oute; partial = pe; lb = b; }
    else          { counts = cn; n = N_NODES; out = outn; partial = pn; lb = b - NB_E; }
    int tid = (int)threadIdx.x;
    int i = lb * 1024 + tid;
    int v = (i < n) ? counts[i] : 0;
    sd[tid] = v;
    __syncthreads();
    for (int off = 1; off < 1024; off <<= 1) {
        int t = (tid >= off) ? sd[tid - off] : 0;
        __syncthreads();
        sd[tid] += t;
        __syncthreads();
    }
    if (i < n) out[i] = sd[tid] - v;
    if (tid == 1023) partial[lb] = sd[1023];
}

// ---------------------------------------------------------------- fused scan p2 (2 waves)
__global__ void k_scan_top2(int* __restrict__ pe, int* __restrict__ pn,
                            int* __restrict__ tot_e, int* __restrict__ tot_n) {
    int w = (int)threadIdx.x >> 6;
    int lane = (int)threadIdx.x & 63;
    int* partial = w ? pn : pe;
    int nb       = w ? NB_N : NB_E;
    int* total   = w ? tot_n : tot_e;
    int v = (lane < nb) ? partial[lane] : 0;
    int incl = v;
    for (int off = 1; off < 64; off <<= 1) {
        int t = __shfl_up(incl, off);
        if (lane >= off) incl += t;
    }
    if (lane < nb) partial[lane] = incl - v;
    if (lane == 63) *total = incl;
}

// ---------------------------------------------------------------- fused scan p3
__global__ __launch_bounds__(1024) void k_scan_add2(int* __restrict__ oute,
                                                    int* __restrict__ outn,
                                                    const int* __restrict__ pe,
                                                    const int* __restrict__ pn) {
    int b = (int)blockIdx.x;
    int* out; const int* partial; int n; int lb;
    if (b < NB_E) { out = oute; partial = pe; n = N_EDGES; lb = b; }
    else          { out = outn; partial = pn; n = N_NODES; lb = b - NB_E; }
    int i = lb * 1024 + (int)threadIdx.x;
    if (i < n) out[i] += partial[lb];
}

// ---------------------------------------------------------------- CSR fill (atomic-free)
__global__ void k_fill(const int* __restrict__ hidx,
                       const int* __restrict__ edge_ptr,
                       const int* __restrict__ node_ptr,
                       const int* __restrict__ rank_e,
                       const int* __restrict__ rank_v,
                       const int* __restrict__ off8_e,
                       const int* __restrict__ off8_n,
                       int* __restrict__ edge_node,
                       int* __restrict__ node_edge) {
    int i = blockIdx.x * blockDim.x + threadIdx.x;
    if (i >= NNZ) return;
    int v = hidx[i];
    int e = hidx[NNZ + i];
    v = min(max(v, 0), N_NODES - 1);
    e = min(max(e, 0), N_EDGES - 1);
    int pe = rank_e[i];
    int pv = rank_v[i];
    int xe = pe >> 24, re = pe & 0xFFFFFF;
    int xv = pv >> 24, rv = pv & 0xFFFFFF;
    edge_node[edge_ptr[e] + off8_e[xe * N_EDGES + e] + re] = v;
    node_edge[node_ptr[v] + off8_n[xv * N_NODES + v] + rv] = e;
}

// ---------------------------------------------------------------- norms from CSR
__global__ void k_norms2(const float* __restrict__ ew,
                         const int* __restrict__ edge_ptr,
                         const int* __restrict__ node_ptr,
                         const int* __restrict__ node_edge,
                         float* __restrict__ dv_is,
                         float* __restrict__ de_w) {
    int i = blockIdx.x * blockDim.x + threadIdx.x;
    if (i < N_NODES) {
        int s = node_ptr[i], t = node_ptr[i + 1];
        float d = 0.f;
        for (int j = s; j < t; ++j) d += ew[node_edge[j]];
        dv_is[i] = (d > 0.f) ? rsqrtf(fmaxf(d, 1e-12f)) : 0.f;
    }
    if (i < N_EDGES) {
        int c = edge_ptr[i + 1] - edge_ptr[i];
        de_w[i] = ew[i] * ((c > 0) ? (1.f / (float)c) : 0.f);
    }
}

// ---------------------------------------------------------------- init
// Buffers hold V = w*T with w = dv_is (or 1 for isolated nodes, which phaseA
// never gathers). acc holds true theta0*x.
__global__ void k_init(const float* __restrict__ x,
                       const float* __restrict__ theta,
                       const float* __restrict__ dv_is,
                       uint4* __restrict__ bufA,
                       float* __restrict__ acc) {
    int i = blockIdx.x * blockDim.x + threadIdx.x;
    if (i >= N_NODES * R16) return;
    int v = i >> 4;
    float dvv = dv_is[v];
    float w = (dvv > 0.f) ? dvv : 1.f;
    float4 x0 = ((const float4*)x)[2 * i];
    float4 x1 = ((const float4*)x)[2 * i + 1];
    uint4 q;
    q.x = pack2(w * x0.x, w * x0.y); q.y = pack2(w * x0.z, w * x0.w);
    q.z = pack2(w * x1.x, w * x1.y); q.w = pack2(w * x1.z, w * x1.w);
    bufA[i] = q;
    float t0 = theta[0];
    float4 a0, a1;
    a0.x = t0 * x0.x; a0.y = t0 * x0.y; a0.z = t0 * x0.z; a0.w = t0 * x0.w;
    a1.x = t0 * x1.x; a1.y = t0 * x1.y; a1.z = t0 * x1.z; a1.w = t0 * x1.w;
    ((float4*)acc)[2 * i]     = a0;
    ((float4*)acc)[2 * i + 1] = a1;
}

// ---------------------------------------------------------------- phase A
// 4 edges/block, one 64-lane wave per edge: 4 member-streams x 16 feature-lanes.
// Rows pre-scaled (V = dv*T): pure unweighted row-sum, 4 rows in flight/stream.
__global__ void k_phaseA(const uint4* __restrict__ tin,
                         const float* __restrict__ de_w,
                         const int* __restrict__ edge_ptr,
                         const int* __restrict__ edge_node,
                         uint4* __restrict__ m_e) {
    int tid    = (int)threadIdx.x;
    int g      = tid >> 6;            // edge slot in block
    int l64    = tid & 63;
    int stream = l64 >> 4;            // 0..3
    int lane   = l64 & 15;
    int e = blockIdx.x * 4 + g;
    int s = edge_ptr[e], t = edge_ptr[e + 1];
    float a0=0.f,a1=0.f,a2=0.f,a3=0.f,a4=0.f,a5=0.f,a6=0.f,a7=0.f;
    int j = s + stream;
    for (; j + 12 < t; j += 16) {   // unroll-4 per stream (stride-4 members)
        int v0 = edge_node[j];
        int v1 = edge_node[j + 4];
        int v2 = edge_node[j + 8];
        int v3 = edge_node[j + 12];
        uint4 q0 = tin[v0 * R16 + lane];
        uint4 q1 = tin[v1 * R16 + lane];
        uint4 q2 = tin[v2 * R16 + lane];
        uint4 q3 = tin[v3 * R16 + lane];
        a0 += (blo(q0.x) + blo(q1.x)) + (blo(q2.x) + blo(q3.x));
        a1 += (bhi(q0.x) + bhi(q1.x)) + (bhi(q2.x) + bhi(q3.x));
        a2 += (blo(q0.y) + blo(q1.y)) + (blo(q2.y) + blo(q3.y));
        a3 += (bhi(q0.y) + bhi(q1.y)) + (bhi(q2.y) + bhi(q3.y));
        a4 += (blo(q0.z) + blo(q1.z)) + (blo(q2.z) + blo(q3.z));
        a5 += (bhi(q0.z) + bhi(q1.z)) + (bhi(q2.z) + bhi(q3.z));
        a6 += (blo(q0.w) + blo(q1.w)) + (blo(q2.w) + blo(q3.w));
        a7 += (bhi(q0.w) + bhi(q1.w)) + (bhi(q2.w) + bhi(q3.w));
    }
    for (; j < t; j += 4) {
        int v0 = edge_node[j];
        uint4 q0 = tin[v0 * R16 + lane];
        a0 += blo(q0.x); a1 += bhi(q0.x);
        a2 += blo(q0.y); a3 += bhi(q0.y);
        a4 += blo(q0.z); a5 += bhi(q0.z);
        a6 += blo(q0.w); a7 += bhi(q0.w);
    }
    // combine the four streams (xor 16 then xor 32 within the wave)
    a0 += __shfl_xor(a0, 16); a1 += __shfl_xor(a1, 16);
    a2 += __shfl_xor(a2, 16); a3 += __shfl_xor(a3, 16);
    a4 += __shfl_xor(a4, 16); a5 += __shfl_xor(a5, 16);
    a6 += __shfl_xor(a6, 16); a7 += __shfl_xor(a7, 16);
    a0 += __shfl_xor(a0, 32); a1 += __shfl_xor(a1, 32);
    a2 += __shfl_xor(a2, 32); a3 += __shfl_xor(a3, 32);
    a4 += __shfl_xor(a4, 32); a5 += __shfl_xor(a5, 32);
    a6 += __shfl_xor(a6, 32); a7 += __shfl_xor(a7, 32);
    if (stream == 0) {
        float w = de_w[e];
        uint4 o;
        o.x = pack2(a0 * w, a1 * w); o.y = pack2(a2 * w, a3 * w);
        o.z = pack2(a4 * w, a5 * w); o.w = pack2(a6 * w, a7 * w);
        m_e[e * R16 + lane] = o;
    }
}

// ---------------------------------------------------------------- phase B
// 8 nodes/block; per node 32 lanes = 2 edge-streams x 16 feature-lanes.
// V_k = ca*dv^2*sum + cb*V_{k-2}.
// accMode: 0 = no acc update; 1 = acc += iw*th_k*V_k;
//          2 = + th_{k-1}*V_{k-1}(tin); 3 = + th_{k-2}*V_{k-2}(tp, free).
__global__ void k_phaseB(const uint4* __restrict__ m_e,
                         const uint4* __restrict__ tin,
                         const float* __restrict__ dv_is,
                         const int* __restrict__ node_ptr,
                         const int* __restrict__ node_edge,
                         uint4* __restrict__ tio,
                         float* __restrict__ acc,
                         const float* __restrict__ theta, int k,
                         float ca, float cb, int accMode) {
    int g      = threadIdx.x >> 5;
    int stream = (threadIdx.x >> 4) & 1;
    int lane   = threadIdx.x & 15;
    int v = blockIdx.x * 8 + g;
    int s = node_ptr[v], t = node_ptr[v + 1];
    float s0=0.f,s1=0.f,s2=0.f,s3=0.f,s4=0.f,s5=0.f,s6=0.f,s7=0.f;
    int j = s + stream;
    for (; j + 2 < t; j += 4) {
        int e0 = node_edge[j];
        int e1 = node_edge[j + 2];
        uint4 q0 = m_e[e0 * R16 + lane];
        uint4 q1 = m_e[e1 * R16 + lane];
        s0 += blo(q0.x) + blo(q1.x); s1 += bhi(q0.x) + bhi(q1.x);
        s2 += blo(q0.y) + blo(q1.y); s3 += bhi(q0.y) + bhi(q1.y);
        s4 += blo(q0.z) + blo(q1.z); s5 += bhi(q0.z) + bhi(q1.z);
        s6 += blo(q0.w) + blo(q1.w); s7 += bhi(q0.w) + bhi(q1.w);
    }
    if (j < t) {
        int e0 = node_edge[j];
        uint4 q0 = m_e[e0 * R16 + lane];
        s0 += blo(q0.x); s1 += bhi(q0.x);
        s2 += blo(q0.y); s3 += bhi(q0.y);
        s4 += blo(q0.z); s5 += bhi(q0.z);
        s6 += blo(q0.w); s7 += bhi(q0.w);
    }
    s0 += __shfl_xor(s0, 16); s1 += __shfl_xor(s1, 16);
    s2 += __shfl_xor(s2, 16); s3 += __shfl_xor(s3, 16);
    s4 += __shfl_xor(s4, 16); s5 += __shfl_xor(s5, 16);
    s6 += __shfl_xor(s6, 16); s7 += __shfl_xor(s7, 16);
    if (stream == 0) {
        float dvv = dv_is[v];
        float scf = ca * dvv * dvv;           // 0 for isolated nodes (sum=0 anyway)
        int idx = v * R16 + lane;
        uint4 tp = tio[idx];
        float t0 = scf * s0 + cb * blo(tp.x);
        float t1 = scf * s1 + cb * bhi(tp.x);
        float t2 = scf * s2 + cb * blo(tp.y);
        float t3 = scf * s3 + cb * bhi(tp.y);
        float t4 = scf * s4 + cb * blo(tp.z);
        float t5 = scf * s5 + cb * bhi(tp.z);
        float t6 = scf * s6 + cb * blo(tp.w);
        float t7 = scf * s7 + cb * bhi(tp.w);
        uint4 tn;
        tn.x = pack2(t0, t1); tn.y = pack2(t2, t3);
        tn.z = pack2(t4, t5); tn.w = pack2(t6, t7);
        tio[idx] = tn;
        if (accMode) {
            float thk = theta[k];
            float a0 = thk * t0, a1 = thk * t1, a2 = thk * t2, a3 = thk * t3;
            float a4 = thk * t4, a5 = thk * t5, a6 = thk * t6, a7 = thk * t7;
            if (accMode >= 2) {
                float th1 = theta[k - 1];
                uint4 tq = tin[idx];          // V_{k-1}, coalesced
                a0 += th1 * blo(tq.x); a1 += th1 * bhi(tq.x);
                a2 += th1 * blo(tq.y); a3 += th1 * bhi(tq.y);
                a4 += th1 * blo(tq.z); a5 += th1 * bhi(tq.z);
                a6 += th1 * blo(tq.w); a7 += th1 * bhi(tq.w);
            }
            if (accMode >= 3) {
                float th2 = theta[k - 2];
                a0 += th2 * blo(tp.x); a1 += th2 * bhi(tp.x);
                a2 += th2 * blo(tp.y); a3 += th2 * bhi(tp.y);
                a4 += th2 * blo(tp.z); a5 += th2 * bhi(tp.z);
                a6 += th2 * blo(tp.w); a7 += th2 * bhi(tp.w);
            }
            float iw = (dvv > 0.f) ? (1.f / dvv) : 1.f;
            float4* acc4 = (float4*)acc;
            int ai = v * 32 + lane * 2;
            float4 a = acc4[ai];
            a.x += iw * a0; a.y += iw * a1; a.z += iw * a2; a.w += iw * a3;
            acc4[ai] = a;
            float4 b = acc4[ai + 1];
            b.x += iw * a4; b.y += iw * a5; b.z += iw * a6; b.w += iw * a7;
            acc4[ai + 1] = b;
        }
    }
}

// ---------------------------------------------------------------- MFMA GEMM
// out = relu(A @ W^T + b), A=accv fp32 [M][128], W fp32 [512][128].
// Block: 256thr=4 waves, tile M=64 N=64, K=128 fully staged.
// fp32->bf16 cast during LDS staging (no extra buffers).
// LDS row = 136 shorts (272B): lane bank spread uniform -> conflict-free.
// XCD swizzle: id&7 = band; each band owns 98 contiguous m-tiles.
#define M_TILES 782
__global__ __launch_bounds__(256) void k_gemm(const float* __restrict__ A,
                                              const float* __restrict__ W,
                                              const float* __restrict__ bias,
                                              float* __restrict__ out) {
    __shared__ short Asm[64 * 136];
    __shared__ short Wsm[64 * 136];
    int id  = (int)blockIdx.x;
    int xcd = id & 7;
    int sub = id >> 3;
    int h_t = sub & 7;
    int m_i = sub >> 3;                 // 0..97
    int m_t = xcd * 98 + m_i;
    if (m_t >= M_TILES) return;
    int m0 = m_t * 64;
    int h0 = h_t * 64;
    int tid = (int)threadIdx.x;

    const float4* A4 = (const float4*)A;
    const float4* W4 = (const float4*)W;
#pragma unroll
    for (int i = 0; i < 4; ++i) {
        int c   = tid + i * 256;        // 0..1023
        int row = c >> 4;               // 0..63
        int q4  = c & 15;               // uint4 column
        int gr = m0 + row;
        float4 a0, a1;
        if (gr < N_NODES) {
            a0 = A4[(size_t)gr * 32 + q4 * 2];
            a1 = A4[(size_t)gr * 32 + q4 * 2 + 1];
        } else {
            a0 = make_float4(0.f, 0.f, 0.f, 0.f);
            a1 = a0;
        }
        uint4 pa;
        pa.x = pack2(a0.x, a0.y); pa.y = pack2(a0.z, a0.w);
        pa.z = pack2(a1.x, a1.y); pa.w = pack2(a1.z, a1.w);
        *(uint4*)&Asm[row * 136 + q4 * 8] = pa;
        float4 w0 = W4[(size_t)(h0 + row) * 32 + q4 * 2];
        float4 w1 = W4[(size_t)(h0 + row) * 32 + q4 * 2 + 1];
        uint4 pw;
        pw.x = pack2(w0.x, w0.y); pw.y = pack2(w0.z, w0.w);
        pw.z = pack2(w1.x, w1.y); pw.w = pack2(w1.z, w1.w);
        *(uint4*)&Wsm[row * 136 + q4 * 8] = pw;
    }
    __syncthreads();

    int lane = tid & 63;
    int wv   = tid >> 6;                // wave 0..3 -> m rows wv*16..+15
    int l16  = lane & 15;
    int quad = lane >> 4;

    f32x4 acc[4];
#pragma unroll
    for (int n = 0; n < 4; ++n) acc[n] = (f32x4){0.f, 0.f, 0.f, 0.f};

#pragma unroll
    for (int ks = 0; ks < 4; ++ks) {
        int k0 = ks * 32;
        // A-frag: A[m = l16][k = quad*8 + j]
        bf16x8 af = *(const bf16x8*)&Asm[(wv * 16 + l16) * 136 + k0 + quad * 8];
#pragma unroll
        for (int n = 0; n < 4; ++n) {
            bf16x8 bf = *(const bf16x8*)&Wsm[(n * 16 + l16) * 136 + k0 + quad * 8];
            acc[n] = __builtin_amdgcn_mfma_f32_16x16x32_bf16(af, bf, acc[n], 0, 0, 0);
        }
    }

    // C/D layout: col = lane&15, row = quad*4 + reg   (m89/m91-verified)
#pragma unroll
    for (int n = 0; n < 4; ++n) {
        float bb = bias[h0 + n * 16 + l16];
#pragma unroll
        for (int r = 0; r < 4; ++r) {
            int gr = m0 + wv * 16 + quad * 4 + r;
            if (gr < N_NODES)
                out[(size_t)gr * HID + h0 + n * 16 + l16] =
                    fmaxf(acc[n][r] + bb, 0.f);
        }
    }
}

// ----------------------------------------------------------------
extern "C" void kernel_launch(void* const* d_in, const int* in_sizes, int n_in,
                              void* d_out, int out_size, void* d_ws, size_t ws_size,
                              hipStream_t stream) {
    const float* x     = (const float*)d_in[0];
    const int*   hidx  = (const int*)d_in[1];    // int32, [2, NNZ] row-major
    const float* ew    = (const float*)d_in[2];
    const float* theta = (const float*)d_in[3];
    const float* w1    = (const float*)d_in[4];
    const float* b1    = (const float*)d_in[5];
    float*       out   = (float*)d_out;
    int kp1 = in_sizes[3];  // K+1 (= 11)
    int K   = kp1 - 1;

    // ---- scratch carved out of d_out (all dead before k_gemm's writes) ----
    char* ob = (char*)d_out;
    size_t oo = 0;
    auto oalloc = [&](size_t bytes) -> void* {
        void* p = ob + oo;
        oo = (oo + bytes + 255) & ~(size_t)255;
        return p;
    };
    uint4* bufA      = (uint4*)oalloc((size_t)N_NODES * F_IN * 2);
    uint4* bufB      = (uint4*)oalloc((size_t)N_NODES * F_IN * 2);
    uint4* m_e       = (uint4*)oalloc((size_t)N_EDGES * F_IN * 2);
    int*   edge_node = (int*)oalloc((size_t)NNZ * 4);
    int*   node_edge = (int*)oalloc((size_t)NNZ * 4);
    int*   rank_e    = (int*)oalloc((size_t)NNZ * 4);
    int*   rank_v    = (int*)oalloc((size_t)NNZ * 4);
    int*   cnt8_e    = (int*)oalloc((size_t)8 * N_EDGES * 4);   // -> off8_e
    int*   cnt8_n    = (int*)oalloc((size_t)8 * N_NODES * 4);   // -> off8_n
    int*   counts_e  = (int*)oalloc((size_t)N_EDGES * 4);
    int*   counts_n  = (int*)oalloc((size_t)N_NODES * 4);

    // ---- d_ws (~26MB) ----
    char* ws = (char*)d_ws;
    size_t off = 0;
    auto alloc = [&](size_t bytes) -> void* {
        void* p = ws + off;
        off = (off + bytes + 255) & ~(size_t)255;
        return p;
    };
    float* accv     = (float*)alloc((size_t)N_NODES * F_IN * 4);
    float* dv_is    = (float*)alloc((size_t)N_NODES * 4);
    float* de_w     = (float*)alloc((size_t)N_EDGES * 4);
    int*   edge_ptr = (int*)alloc((size_t)(N_EDGES + 1) * 4);
    int*   node_ptr = (int*)alloc((size_t)(N_NODES + 1) * 4);
    int*   part_e   = (int*)alloc(64 * 4);
    int*   part_n   = (int*)alloc(64 * 4);

    k_zero8<<<(8 * N_NODES + 255) / 256, 256, 0, stream>>>(cnt8_e, cnt8_n);
    k_degrees<<<(NNZ + 255) / 256, 256, 0, stream>>>(hidx, cnt8_e, cnt8_n, rank_e, rank_v);
    k_off8<<<(N_NODES + 255) / 256, 256, 0, stream>>>(cnt8_e, cnt8_n, counts_e, counts_n);

    k_scan_blk2<<<NB_E + NB_N, 1024, 0, stream>>>(counts_e, counts_n, edge_ptr, node_ptr,
                                                  part_e, part_n);
    k_scan_top2<<<1, 128, 0, stream>>>(part_e, part_n, edge_ptr + N_EDGES, node_ptr + N_NODES);
    k_scan_add2<<<NB_E + NB_N, 1024, 0, stream>>>(edge_ptr, node_ptr, part_e, part_n);

    k_fill<<<(NNZ + 255) / 256, 256, 0, stream>>>(hidx, edge_ptr, node_ptr,
                                                  rank_e, rank_v, cnt8_e, cnt8_n,
                                                  edge_node, node_edge);
    k_norms2<<<(N_NODES + 255) / 256, 256, 0, stream>>>(ew, edge_ptr, node_ptr,
                                                        node_edge, dv_is, de_w);
    k_init<<<(N_NODES * R16 + 255) / 256, 256, 0, stream>>>(x, theta, dv_is, bufA, accv);

    for (int k = 1; k <= K; ++k) {
        const uint4* tin = (k & 1) ? bufA : bufB;   // V_{k-1}
        uint4*       tio = (k & 1) ? bufB : bufA;   // V_{k-2} -> V_k (in place)
        float ca = (k == 1) ? -1.f : -2.f;
        float cb = (k == 1) ? 0.f : -1.f;
        // grouped theta accumulation: every 3rd step banks th_{k-2},th_{k-1},th_k;
        // the final step banks the K%3 leftover terms.
        int accMode = 0;
        if (k % 3 == 0) accMode = 3;
        else if (k == K && (K % 3) != 0) accMode = K % 3;
        k_phaseA<<<N_EDGES / 4, 256, 0, stream>>>(tin, de_w, edge_ptr, edge_node, m_e);
        k_phaseB<<<N_NODES / 8, 256, 0, stream>>>(m_e, tin, dv_is, node_ptr, node_edge,
                                                  tio, accv, theta, k, ca, cb, accMode);
    }

    // 8 bands x 98 m-tiles x 8 h-tiles (2 tail tiles early-return)
    k_gemm<<<8 * 98 * 8, 256, 0, stream>>>(accv, w1, b1, out);
}

// Round 3
// 745.370 us; speedup vs baseline: 1.1115x; 1.0387x over previous
//
#include <hip/hip_runtime.h>

// HypergraphGuidedChebNet on MI355X.
//   1. k_hist: per-block LDS histograms (packed 16-bit) + local-rank capture
//   2. k_combine: per-key replica bases + totals  3. fused scans
//   4. fill CSR (atomic-free)  5. norms2  6. init (pre-scaled V0 = dv*x)
//   7. 10x [phaseA edge-gather (4-stream waves), phaseB node-gather with
//      GROUPED theta accumulation (k=3,6,9: 3 terms, k=10: 1)]
//   8. bf16 MFMA GEMM (fp32->bf16 cast in staging), XCD-banded swizzle
//
// Round 10 theory:
//   - k_degrees' WRITE_SIZE 56MB = 1.6M x 32B proves device-scope atomics are
//     memory-side write-through at ~25Gop/s on gfx950 -> no global-atomic
//     arrangement beats 64us. Replaced with LDS histogram counting-sort:
//     64 blocks x 1024thr, 120KB LDS (nodes 25K packed words + edges 5K),
//     LDS atomicAdd returns local rank (ushort), per-block hists + combine
//     give exclusive bases. Zero global returning atomics.
//   - phases / GEMM unchanged this round.

#define N_NODES 50000
#define N_EDGES 10000
#define NNZ     800000
#define F_IN    128
#define HID     512
#define F4      (F_IN / 4)
#define R16     16           // 16 uint4 per bf16 row
#define NB_E    10           // scan blocks, edges
#define NB_N    49           // scan blocks, nodes
#define HB      64           // histogram blocks
#define NW_E    (N_EDGES / 2)    // packed words, edges
#define NW_N    (N_NODES / 2)    // packed words, nodes

typedef __attribute__((ext_vector_type(8))) short bf16x8;
typedef __attribute__((ext_vector_type(4))) float f32x4;

static __device__ __forceinline__ unsigned short f2bf(float f) {
    union { float f; unsigned u; } c; c.f = f;
    unsigned u = c.u;
    unsigned r = (u + 0x7fffu + ((u >> 16) & 1u)) >> 16;
    return (unsigned short)r;
}
static __device__ __forceinline__ float blo(unsigned u) {
    union { unsigned u; float f; } c; c.u = u << 16; return c.f;
}
static __device__ __forceinline__ float bhi(unsigned u) {
    union { unsigned u; float f; } c; c.u = u & 0xffff0000u; return c.f;
}
static __device__ __forceinline__ unsigned pack2(float lo, float hi) {
    return (unsigned)f2bf(lo) | ((unsigned)f2bf(hi) << 16);
}

// ---------------------------------------------------------------- LDS histogram + ranks
// 64 blocks x 1024 threads, grid-stride. Packed 16-bit counters per key pair.
// Per-block element count <= ceil(800000/65536)*1024 = 13312 < 65536: no carry.
__global__ __launch_bounds__(1024) void k_hist(const int* __restrict__ hidx,
                                               unsigned short* __restrict__ loc_e,
                                               unsigned short* __restrict__ loc_v,
                                               unsigned* __restrict__ hist_e,
                                               unsigned* __restrict__ hist_n) {
    __shared__ unsigned she[NW_E];
    __shared__ unsigned shn[NW_N];
    int tid = (int)threadIdx.x;
    for (int w = tid; w < NW_E; w += 1024) she[w] = 0;
    for (int w = tid; w < NW_N; w += 1024) shn[w] = 0;
    __syncthreads();
    int bid = (int)blockIdx.x;
    for (int i = bid * 1024 + tid; i < NNZ; i += HB * 1024) {
        int v = hidx[i];
        int e = hidx[NNZ + i];
        v = min(max(v, 0), N_NODES - 1);
        e = min(max(e, 0), N_EDGES - 1);
        int se = (e & 1) * 16;
        int sv = (v & 1) * 16;
        unsigned oe = atomicAdd(&she[e >> 1], 1u << se);
        unsigned ov = atomicAdd(&shn[v >> 1], 1u << sv);
        loc_e[i] = (unsigned short)((oe >> se) & 0xFFFFu);
        loc_v[i] = (unsigned short)((ov >> sv) & 0xFFFFu);
    }
    __syncthreads();
    for (int w = tid; w < NW_E; w += 1024) hist_e[bid * NW_E + w] = she[w];
    for (int w = tid; w < NW_N; w += 1024) hist_n[bid * NW_N + w] = shn[w];
}

// ---------------------------------------------------------------- replica combine
// Per key: exclusive running sum over the 64 block-histograms -> bases + total.
__global__ void k_combine(const unsigned* __restrict__ hist_e,
                          const unsigned* __restrict__ hist_n,
                          int* __restrict__ base_e,
                          int* __restrict__ base_n,
                          int* __restrict__ counts_e,
                          int* __restrict__ counts_n) {
    int i = blockIdx.x * blockDim.x + threadIdx.x;
    if (i < N_EDGES) {
        int sh = (i & 1) * 16;
        int w = i >> 1;
        int s = 0;
#pragma unroll 8
        for (int b = 0; b < HB; ++b) {
            base_e[b * N_EDGES + i] = s;
            s += (int)((hist_e[b * NW_E + w] >> sh) & 0xFFFFu);
        }
        counts_e[i] = s;
    }
    if (i < N_NODES) {
        int sh = (i & 1) * 16;
        int w = i >> 1;
        int s = 0;
#pragma unroll 8
        for (int b = 0; b < HB; ++b) {
            base_n[b * N_NODES + i] = s;
            s += (int)((hist_n[b * NW_N + w] >> sh) & 0xFFFFu);
        }
        counts_n[i] = s;
    }
}

// ---------------------------------------------------------------- fused scan p1 (edges+nodes)
__global__ __launch_bounds__(1024) void k_scan_blk2(const int* __restrict__ ce,
                                                    const int* __restrict__ cn,
                                                    int* __restrict__ oute,
                                                    int* __restrict__ outn,
                                                    int* __restrict__ pe,
                                                    int* __restrict__ pn) {
    __shared__ int sd[1024];
    int b = (int)blockIdx.x;
    const int* counts; int n; int* out; int* partial; int lb;
    if (b < NB_E) { counts = ce; n = N_EDGES; out = oute; partial = pe; lb = b; }
    else          { counts = cn; n = N_NODES; out = outn; partial = pn; lb = b - NB_E; }
    int tid = (int)threadIdx.x;
    int i = lb * 1024 + tid;
    int v = (i < n) ? counts[i] : 0;
    sd[tid] = v;
    __syncthreads();
    for (int off = 1; off < 1024; off <<= 1) {
        int t = (tid >= off) ? sd[tid - off] : 0;
        __syncthreads();
        sd[tid] += t;
        __syncthreads();
    }
    if (i < n) out[i] = sd[tid] - v;
    if (tid == 1023) partial[lb] = sd[1023];
}

// ---------------------------------------------------------------- fused scan p2 (2 waves)
__global__ void k_scan_top2(int* __restrict__ pe, int* __restrict__ pn,
                            int* __restrict__ tot_e, int* __restrict__ tot_n) {
    int w = (int)threadIdx.x >> 6;
    int lane = (int)threadIdx.x & 63;
    int* partial = w ? pn : pe;
    int nb       = w ? NB_N : NB_E;
    int* total   = w ? tot_n : tot_e;
    int v = (lane < nb) ? partial[lane] : 0;
    int incl = v;
    for (int off = 1; off < 64; off <<= 1) {
        int t = __shfl_up(incl, off);
        if (lane >= off) incl += t;
    }
    if (lane < nb) partial[lane] = incl - v;
    if (lane == 63) *total = incl;
}

// ---------------------------------------------------------------- fused scan p3
__global__ __launch_bounds__(1024) void k_scan_add2(int* __restrict__ oute,
                                                    int* __restrict__ outn,
                                                    const int* __restrict__ pe,
                                                    const int* __restrict__ pn) {
    int b = (int)blockIdx.x;
    int* out; const int* partial; int n; int lb;
    if (b < NB_E) { out = oute; partial = pe; n = N_EDGES; lb = b; }
    else          { out = outn; partial = pn; n = N_NODES; lb = b - NB_E; }
    int i = lb * 1024 + (int)threadIdx.x;
    if (i < n) out[i] += partial[lb];
}

// ---------------------------------------------------------------- CSR fill (atomic-free)
// Element i was processed by hist block wg = (i>>10)&63 (grid-stride mapping).
__global__ void k_fill(const int* __restrict__ hidx,
                       const int* __restrict__ edge_ptr,
                       const int* __restrict__ node_ptr,
                       const unsigned short* __restrict__ loc_e,
                       const unsigned short* __restrict__ loc_v,
                       const int* __restrict__ base_e,
                       const int* __restrict__ base_n,
                       int* __restrict__ edge_node,
                       int* __restrict__ node_edge) {
    int i = blockIdx.x * blockDim.x + threadIdx.x;
    if (i >= NNZ) return;
    int wg = (i >> 10) & (HB - 1);
    int v = hidx[i];
    int e = hidx[NNZ + i];
    v = min(max(v, 0), N_NODES - 1);
    e = min(max(e, 0), N_EDGES - 1);
    edge_node[edge_ptr[e] + base_e[wg * N_EDGES + e] + (int)loc_e[i]] = v;
    node_edge[node_ptr[v] + base_n[wg * N_NODES + v] + (int)loc_v[i]] = e;
}

// ---------------------------------------------------------------- norms from CSR
__global__ void k_norms2(const float* __restrict__ ew,
                         const int* __restrict__ edge_ptr,
                         const int* __restrict__ node_ptr,
                         const int* __restrict__ node_edge,
                         float* __restrict__ dv_is,
                         float* __restrict__ de_w) {
    int i = blockIdx.x * blockDim.x + threadIdx.x;
    if (i < N_NODES) {
        int s = node_ptr[i], t = node_ptr[i + 1];
        float d = 0.f;
        for (int j = s; j < t; ++j) d += ew[node_edge[j]];
        dv_is[i] = (d > 0.f) ? rsqrtf(fmaxf(d, 1e-12f)) : 0.f;
    }
    if (i < N_EDGES) {
        int c = edge_ptr[i + 1] - edge_ptr[i];
        de_w[i] = ew[i] * ((c > 0) ? (1.f / (float)c) : 0.f);
    }
}

// ---------------------------------------------------------------- init
// Buffers hold V = w*T with w = dv_is (or 1 for isolated nodes, which phaseA
// never gathers). acc holds true theta0*x.
__global__ void k_init(const float* __restrict__ x,
                       const float* __restrict__ theta,
                       const float* __restrict__ dv_is,
                       uint4* __restrict__ bufA,
                       float* __restrict__ acc) {
    int i = blockIdx.x * blockDim.x + threadIdx.x;
    if (i >= N_NODES * R16) return;
    int v = i >> 4;
    float dvv = dv_is[v];
    float w = (dvv > 0.f) ? dvv : 1.f;
    float4 x0 = ((const float4*)x)[2 * i];
    float4 x1 = ((const float4*)x)[2 * i + 1];
    uint4 q;
    q.x = pack2(w * x0.x, w * x0.y); q.y = pack2(w * x0.z, w * x0.w);
    q.z = pack2(w * x1.x, w * x1.y); q.w = pack2(w * x1.z, w * x1.w);
    bufA[i] = q;
    float t0 = theta[0];
    float4 a0, a1;
    a0.x = t0 * x0.x; a0.y = t0 * x0.y; a0.z = t0 * x0.z; a0.w = t0 * x0.w;
    a1.x = t0 * x1.x; a1.y = t0 * x1.y; a1.z = t0 * x1.z; a1.w = t0 * x1.w;
    ((float4*)acc)[2 * i]     = a0;
    ((float4*)acc)[2 * i + 1] = a1;
}

// ---------------------------------------------------------------- phase A
// 4 edges/block, one 64-lane wave per edge: 4 member-streams x 16 feature-lanes.
// Rows pre-scaled (V = dv*T): pure unweighted row-sum, 4 rows in flight/stream.
__global__ void k_phaseA(const uint4* __restrict__ tin,
                         const float* __restrict__ de_w,
                         const int* __restrict__ edge_ptr,
                         const int* __restrict__ edge_node,
                         uint4* __restrict__ m_e) {
    int tid    = (int)threadIdx.x;
    int g      = tid >> 6;            // edge slot in block
    int l64    = tid & 63;
    int stream = l64 >> 4;            // 0..3
    int lane   = l64 & 15;
    int e = blockIdx.x * 4 + g;
    int s = edge_ptr[e], t = edge_ptr[e + 1];
    float a0=0.f,a1=0.f,a2=0.f,a3=0.f,a4=0.f,a5=0.f,a6=0.f,a7=0.f;
    int j = s + stream;
    for (; j + 12 < t; j += 16) {   // unroll-4 per stream (stride-4 members)
        int v0 = edge_node[j];
        int v1 = edge_node[j + 4];
        int v2 = edge_node[j + 8];
        int v3 = edge_node[j + 12];
        uint4 q0 = tin[v0 * R16 + lane];
        uint4 q1 = tin[v1 * R16 + lane];
        uint4 q2 = tin[v2 * R16 + lane];
        uint4 q3 = tin[v3 * R16 + lane];
        a0 += (blo(q0.x) + blo(q1.x)) + (blo(q2.x) + blo(q3.x));
        a1 += (bhi(q0.x) + bhi(q1.x)) + (bhi(q2.x) + bhi(q3.x));
        a2 += (blo(q0.y) + blo(q1.y)) + (blo(q2.y) + blo(q3.y));
        a3 += (bhi(q0.y) + bhi(q1.y)) + (bhi(q2.y) + bhi(q3.y));
        a4 += (blo(q0.z) + blo(q1.z)) + (blo(q2.z) + blo(q3.z));
        a5 += (bhi(q0.z) + bhi(q1.z)) + (bhi(q2.z) + bhi(q3.z));
        a6 += (blo(q0.w) + blo(q1.w)) + (blo(q2.w) + blo(q3.w));
        a7 += (bhi(q0.w) + bhi(q1.w)) + (bhi(q2.w) + bhi(q3.w));
    }
    for (; j < t; j += 4) {
        int v0 = edge_node[j];
        uint4 q0 = tin[v0 * R16 + lane];
        a0 += blo(q0.x); a1 += bhi(q0.x);
        a2 += blo(q0.y); a3 += bhi(q0.y);
        a4 += blo(q0.z); a5 += bhi(q0.z);
        a6 += blo(q0.w); a7 += bhi(q0.w);
    }
    // combine the four streams (xor 16 then xor 32 within the wave)
    a0 += __shfl_xor(a0, 16); a1 += __shfl_xor(a1, 16);
    a2 += __shfl_xor(a2, 16); a3 += __shfl_xor(a3, 16);
    a4 += __shfl_xor(a4, 16); a5 += __shfl_xor(a5, 16);
    a6 += __shfl_xor(a6, 16); a7 += __shfl_xor(a7, 16);
    a0 += __shfl_xor(a0, 32); a1 += __shfl_xor(a1, 32);
    a2 += __shfl_xor(a2, 32); a3 += __shfl_xor(a3, 32);
    a4 += __shfl_xor(a4, 32); a5 += __shfl_xor(a5, 32);
    a6 += __shfl_xor(a6, 32); a7 += __shfl_xor(a7, 32);
    if (stream == 0) {
        float w = de_w[e];
        uint4 o;
        o.x = pack2(a0 * w, a1 * w); o.y = pack2(a2 * w, a3 * w);
        o.z = pack2(a4 * w, a5 * w); o.w = pack2(a6 * w, a7 * w);
        m_e[e * R16 + lane] = o;
    }
}

// ---------------------------------------------------------------- phase B
// 8 nodes/block; per node 32 lanes = 2 edge-streams x 16 feature-lanes.
// V_k = ca*dv^2*sum + cb*V_{k-2}.
// accMode: 0 = no acc update; 1 = acc += iw*th_k*V_k;
//          2 = + th_{k-1}*V_{k-1}(tin); 3 = + th_{k-2}*V_{k-2}(tp, free).
__global__ void k_phaseB(const uint4* __restrict__ m_e,
                         const uint4* __restrict__ tin,
                         const float* __restrict__ dv_is,
                         const int* __restrict__ node_ptr,
                         const int* __restrict__ node_edge,
                         uint4* __restrict__ tio,
                         float* __restrict__ acc,
                         const float* __restrict__ theta, int k,
                         float ca, float cb, int accMode) {
    int g      = threadIdx.x >> 5;
    int stream = (threadIdx.x >> 4) & 1;
    int lane   = threadIdx.x & 15;
    int v = blockIdx.x * 8 + g;
    int s = node_ptr[v], t = node_ptr[v + 1];
    float s0=0.f,s1=0.f,s2=0.f,s3=0.f,s4=0.f,s5=0.f,s6=0.f,s7=0.f;
    int j = s + stream;
    for (; j + 2 < t; j += 4) {
        int e0 = node_edge[j];
        int e1 = node_edge[j + 2];
        uint4 q0 = m_e[e0 * R16 + lane];
        uint4 q1 = m_e[e1 * R16 + lane];
        s0 += blo(q0.x) + blo(q1.x); s1 += bhi(q0.x) + bhi(q1.x);
        s2 += blo(q0.y) + blo(q1.y); s3 += bhi(q0.y) + bhi(q1.y);
        s4 += blo(q0.z) + blo(q1.z); s5 += bhi(q0.z) + bhi(q1.z);
        s6 += blo(q0.w) + blo(q1.w); s7 += bhi(q0.w) + bhi(q1.w);
    }
    if (j < t) {
        int e0 = node_edge[j];
        uint4 q0 = m_e[e0 * R16 + lane];
        s0 += blo(q0.x); s1 += bhi(q0.x);
        s2 += blo(q0.y); s3 += bhi(q0.y);
        s4 += blo(q0.z); s5 += bhi(q0.z);
        s6 += blo(q0.w); s7 += bhi(q0.w);
    }
    s0 += __shfl_xor(s0, 16); s1 += __shfl_xor(s1, 16);
    s2 += __shfl_xor(s2, 16); s3 += __shfl_xor(s3, 16);
    s4 += __shfl_xor(s4, 16); s5 += __shfl_xor(s5, 16);
    s6 += __shfl_xor(s6, 16); s7 += __shfl_xor(s7, 16);
    if (stream == 0) {
        float dvv = dv_is[v];
        float scf = ca * dvv * dvv;           // 0 for isolated nodes (sum=0 anyway)
        int idx = v * R16 + lane;
        uint4 tp = tio[idx];
        float t0 = scf * s0 + cb * blo(tp.x);
        float t1 = scf * s1 + cb * bhi(tp.x);
        float t2 = scf * s2 + cb * blo(tp.y);
        float t3 = scf * s3 + cb * bhi(tp.y);
        float t4 = scf * s4 + cb * blo(tp.z);
        float t5 = scf * s5 + cb * bhi(tp.z);
        float t6 = scf * s6 + cb * blo(tp.w);
        float t7 = scf * s7 + cb * bhi(tp.w);
        uint4 tn;
        tn.x = pack2(t0, t1); tn.y = pack2(t2, t3);
        tn.z = pack2(t4, t5); tn.w = pack2(t6, t7);
        tio[idx] = tn;
        if (accMode) {
            float thk = theta[k];
            float a0 = thk * t0, a1 = thk * t1, a2 = thk * t2, a3 = thk * t3;
            float a4 = thk * t4, a5 = thk * t5, a6 = thk * t6, a7 = thk * t7;
            if (accMode >= 2) {
                float th1 = theta[k - 1];
                uint4 tq = tin[idx];          // V_{k-1}, coalesced
                a0 += th1 * blo(tq.x); a1 += th1 * bhi(tq.x);
                a2 += th1 * blo(tq.y); a3 += th1 * bhi(tq.y);
                a4 += th1 * blo(tq.z); a5 += th1 * bhi(tq.z);
                a6 += th1 * blo(tq.w); a7 += th1 * bhi(tq.w);
            }
            if (accMode >= 3) {
                float th2 = theta[k - 2];
                a0 += th2 * blo(tp.x); a1 += th2 * bhi(tp.x);
                a2 += th2 * blo(tp.y); a3 += th2 * bhi(tp.y);
                a4 += th2 * blo(tp.z); a5 += th2 * bhi(tp.z);
                a6 += th2 * blo(tp.w); a7 += th2 * bhi(tp.w);
            }
            float iw = (dvv > 0.f) ? (1.f / dvv) : 1.f;
            float4* acc4 = (float4*)acc;
            int ai = v * 32 + lane * 2;
            float4 a = acc4[ai];
            a.x += iw * a0; a.y += iw * a1; a.z += iw * a2; a.w += iw * a3;
            acc4[ai] = a;
            float4 b = acc4[ai + 1];
            b.x += iw * a4; b.y += iw * a5; b.z += iw * a6; b.w += iw * a7;
            acc4[ai + 1] = b;
        }
    }
}

// ---------------------------------------------------------------- MFMA GEMM
// out = relu(A @ W^T + b), A=accv fp32 [M][128], W fp32 [512][128].
// Block: 256thr=4 waves, tile M=64 N=64, K=128 fully staged.
// fp32->bf16 cast during LDS staging (no extra buffers).
// LDS row = 136 shorts (272B): lane bank spread uniform -> conflict-free.
// XCD swizzle: id&7 = band; each band owns 98 contiguous m-tiles.
#define M_TILES 782
__global__ __launch_bounds__(256) void k_gemm(const float* __restrict__ A,
                                              const float* __restrict__ W,
                                              const float* __restrict__ bias,
                                              float* __restrict__ out) {
    __shared__ short Asm[64 * 136];
    __shared__ short Wsm[64 * 136];
    int id  = (int)blockIdx.x;
    int xcd = id & 7;
    int sub = id >> 3;
    int h_t = sub & 7;
    int m_i = sub >> 3;                 // 0..97
    int m_t = xcd * 98 + m_i;
    if (m_t >= M_TILES) return;
    int m0 = m_t * 64;
    int h0 = h_t * 64;
    int tid = (int)threadIdx.x;

    const float4* A4 = (const float4*)A;
    const float4* W4 = (const float4*)W;
#pragma unroll
    for (int i = 0; i < 4; ++i) {
        int c   = tid + i * 256;        // 0..1023
        int row = c >> 4;               // 0..63
        int q4  = c & 15;               // uint4 column
        int gr = m0 + row;
        float4 a0, a1;
        if (gr < N_NODES) {
            a0 = A4[(size_t)gr * 32 + q4 * 2];
            a1 = A4[(size_t)gr * 32 + q4 * 2 + 1];
        } else {
            a0 = make_float4(0.f, 0.f, 0.f, 0.f);
            a1 = a0;
        }
        uint4 pa;
        pa.x = pack2(a0.x, a0.y); pa.y = pack2(a0.z, a0.w);
        pa.z = pack2(a1.x, a1.y); pa.w = pack2(a1.z, a1.w);
        *(uint4*)&Asm[row * 136 + q4 * 8] = pa;
        float4 w0 = W4[(size_t)(h0 + row) * 32 + q4 * 2];
        float4 w1 = W4[(size_t)(h0 + row) * 32 + q4 * 2 + 1];
        uint4 pw;
        pw.x = pack2(w0.x, w0.y); pw.y = pack2(w0.z, w0.w);
        pw.z = pack2(w1.x, w1.y); pw.w = pack2(w1.z, w1.w);
        *(uint4*)&Wsm[row * 136 + q4 * 8] = pw;
    }
    __syncthreads();

    int lane = tid & 63;
    int wv   = tid >> 6;                // wave 0..3 -> m rows wv*16..+15
    int l16  = lane & 15;
    int quad = lane >> 4;

    f32x4 acc[4];
#pragma unroll
    for (int n = 0; n < 4; ++n) acc[n] = (f32x4){0.f, 0.f, 0.f, 0.f};

#pragma unroll
    for (int ks = 0; ks < 4; ++ks) {
        int k0 = ks * 32;
        // A-frag: A[m = l16][k = quad*8 + j]
        bf16x8 af = *(const bf16x8*)&Asm[(wv * 16 + l16) * 136 + k0 + quad * 8];
#pragma unroll
        for (int n = 0; n < 4; ++n) {
            bf16x8 bf = *(const bf16x8*)&Wsm[(n * 16 + l16) * 136 + k0 + quad * 8];
            acc[n] = __builtin_amdgcn_mfma_f32_16x16x32_bf16(af, bf, acc[n], 0, 0, 0);
        }
    }

    // C/D layout: col = lane&15, row = quad*4 + reg   (m89/m91-verified)
#pragma unroll
    for (int n = 0; n < 4; ++n) {
        float bb = bias[h0 + n * 16 + l16];
#pragma unroll
        for (int r = 0; r < 4; ++r) {
            int gr = m0 + wv * 16 + quad * 4 + r;
            if (gr < N_NODES)
                out[(size_t)gr * HID + h0 + n * 16 + l16] =
                    fmaxf(acc[n][r] + bb, 0.f);
        }
    }
}

// ----------------------------------------------------------------
extern "C" void kernel_launch(void* const* d_in, const int* in_sizes, int n_in,
                              void* d_out, int out_size, void* d_ws, size_t ws_size,
                              hipStream_t stream) {
    const float* x     = (const float*)d_in[0];
    const int*   hidx  = (const int*)d_in[1];    // int32, [2, NNZ] row-major
    const float* ew    = (const float*)d_in[2];
    const float* theta = (const float*)d_in[3];
    const float* w1    = (const float*)d_in[4];
    const float* b1    = (const float*)d_in[5];
    float*       out   = (float*)d_out;
    int kp1 = in_sizes[3];  // K+1 (= 11)
    int K   = kp1 - 1;

    // ---- scratch carved out of d_out (all dead before k_gemm's writes) ----
    char* ob = (char*)d_out;
    size_t oo = 0;
    auto oalloc = [&](size_t bytes) -> void* {
        void* p = ob + oo;
        oo = (oo + bytes + 255) & ~(size_t)255;
        return p;
    };
    uint4* bufA      = (uint4*)oalloc((size_t)N_NODES * F_IN * 2);
    uint4* bufB      = (uint4*)oalloc((size_t)N_NODES * F_IN * 2);
    uint4* m_e       = (uint4*)oalloc((size_t)N_EDGES * F_IN * 2);
    int*   edge_node = (int*)oalloc((size_t)NNZ * 4);
    int*   node_edge = (int*)oalloc((size_t)NNZ * 4);
    unsigned short* loc_e = (unsigned short*)oalloc((size_t)NNZ * 2);
    unsigned short* loc_v = (unsigned short*)oalloc((size_t)NNZ * 2);
    unsigned* hist_e = (unsigned*)oalloc((size_t)HB * NW_E * 4);
    unsigned* hist_n = (unsigned*)oalloc((size_t)HB * NW_N * 4);
    int*   base_e    = (int*)oalloc((size_t)HB * N_EDGES * 4);
    int*   base_n    = (int*)oalloc((size_t)HB * N_NODES * 4);
    int*   counts_e  = (int*)oalloc((size_t)N_EDGES * 4);
    int*   counts_n  = (int*)oalloc((size_t)N_NODES * 4);

    // ---- d_ws (~26MB) ----
    char* ws = (char*)d_ws;
    size_t off = 0;
    auto alloc = [&](size_t bytes) -> void* {
        void* p = ws + off;
        off = (off + bytes + 255) & ~(size_t)255;
        return p;
    };
    float* accv     = (float*)alloc((size_t)N_NODES * F_IN * 4);
    float* dv_is    = (float*)alloc((size_t)N_NODES * 4);
    float* de_w     = (float*)alloc((size_t)N_EDGES * 4);
    int*   edge_ptr = (int*)alloc((size_t)(N_EDGES + 1) * 4);
    int*   node_ptr = (int*)alloc((size_t)(N_NODES + 1) * 4);
    int*   part_e   = (int*)alloc(64 * 4);
    int*   part_n   = (int*)alloc(64 * 4);

    k_hist<<<HB, 1024, 0, stream>>>(hidx, loc_e, loc_v, hist_e, hist_n);
    k_combine<<<(N_NODES + 255) / 256, 256, 0, stream>>>(hist_e, hist_n,
                                                         base_e, base_n,
                                                         counts_e, counts_n);

    k_scan_blk2<<<NB_E + NB_N, 1024, 0, stream>>>(counts_e, counts_n, edge_ptr, node_ptr,
                                                  part_e, part_n);
    k_scan_top2<<<1, 128, 0, stream>>>(part_e, part_n, edge_ptr + N_EDGES, node_ptr + N_NODES);
    k_scan_add2<<<NB_E + NB_N, 1024, 0, stream>>>(edge_ptr, node_ptr, part_e, part_n);

    k_fill<<<(NNZ + 255) / 256, 256, 0, stream>>>(hidx, edge_ptr, node_ptr,
                                                  loc_e, loc_v, base_e, base_n,
                                                  edge_node, node_edge);
    k_norms2<<<(N_NODES + 255) / 256, 256, 0, stream>>>(ew, edge_ptr, node_ptr,
                                                        node_edge, dv_is, de_w);
    k_init<<<(N_NODES * R16 + 255) / 256, 256, 0, stream>>>(x, theta, dv_is, bufA, accv);

    for (int k = 1; k <= K; ++k) {
        const uint4* tin = (k & 1) ? bufA : bufB;   // V_{k-1}
        uint4*       tio = (k & 1) ? bufB : bufA;   // V_{k-2} -> V_k (in place)
        float ca = (k == 1) ? -1.f : -2.f;
        float cb = (k == 1) ? 0.f : -1.f;
        // grouped theta accumulation: every 3rd step banks th_{k-2},th_{k-1},th_k;
        // the final step banks the K%3 leftover terms.
        int accMode = 0;
        if (k % 3 == 0) accMode = 3;
        else if (k == K && (K % 3) != 0) accMode = K % 3;
        k_phaseA<<<N_EDGES / 4, 256, 0, stream>>>(tin, de_w, edge_ptr, edge_node, m_e);
        k_phaseB<<<N_NODES / 8, 256, 0, stream>>>(m_e, tin, dv_is, node_ptr, node_edge,
                                                  tio, accv, theta, k, ca, cb, accMode);
    }

    // 8 bands x 98 m-tiles x 8 h-tiles (2 tail tiles early-return)
    k_gemm<<<8 * 98 * 8, 256, 0, stream>>>(accv, w1, b1, out);
}